// Round 1
// baseline (225.620 us; speedup 1.0000x reference)
//
#include <hip/hip_runtime.h>
#include <hip/hip_bf16.h>
#include <math.h>

// Problem constants (from reference)
#define CCH   256      // IN_CHANNELS
#define HH    128
#define WW    128
#define EPSF  1e-12f
#define SLOPE 0.2f

// pooled layout: [3][N][512]  (c -> mean part, 256+c -> std part)

__global__ __launch_bounds__(256) void stats_kernel(const float* __restrict__ feat,
                                                    float* __restrict__ pooled,
                                                    int N) {
    __shared__ float plane[HH * WW];          // 64 KB
    __shared__ float redA[256];
    __shared__ float redB[256];

    const int p   = blockIdx.x;               // n*C + c
    const int n   = p >> 8;                   // /256
    const int c   = p & 255;
    const int tid = threadIdx.x;

    // ---- stage plane into LDS (coalesced float4) ----
    const float4* src4 = reinterpret_cast<const float4*>(feat + (size_t)p * (HH * WW));
    float4* pl4 = reinterpret_cast<float4*>(plane);
    #pragma unroll
    for (int i = 0; i < (HH * WW / 4) / 256; ++i)
        pl4[tid + i * 256] = src4[tid + i * 256];
    __syncthreads();

    // =============== K = 3, stride 1, out 126x126 (per-thread windows) ===============
    {
        const int OUT = 126;
        float am = 0.f, as = 0.f;
        for (int idx = tid; idx < OUT * OUT; idx += 256) {
            int i = idx / OUT, j = idx - i * OUT;
            float s = 0.f, q = 0.f;
            #pragma unroll
            for (int di = 0; di < 3; ++di) {
                const float* row = &plane[(i + di) * WW + j];
                #pragma unroll
                for (int dj = 0; dj < 3; ++dj) { float v = row[dj]; s += v; q += v * v; }
            }
            float mean = s * (1.f / 9.f);
            float var  = fmaxf(q * (1.f / 9.f) - mean * mean, 0.f);
            am += mean;
            as += sqrtf(var + EPSF);
        }
        redA[tid] = am; redB[tid] = as;
        __syncthreads();
        for (int s = 128; s > 0; s >>= 1) {
            if (tid < s) { redA[tid] += redA[tid + s]; redB[tid] += redB[tid + s]; }
            __syncthreads();
        }
        if (tid == 0) {
            float inv = 1.f / (OUT * OUT);
            pooled[(0 * N + n) * 512 + c]        = redA[0] * inv;
            pooled[(0 * N + n) * 512 + 256 + c]  = redB[0] * inv;
        }
        __syncthreads();
    }

    // =============== K = 34, stride 16, out 6x6 (per-wave windows) ===============
    {
        const int K = 34, S = 16, OUTD = 6, NW = OUTD * OUTD;
        const int wave = tid >> 6, lane = tid & 63;
        float am = 0.f, as = 0.f;
        for (int w = wave; w < NW; w += 4) {
            int wi = w / OUTD, wj = w - wi * OUTD;
            int r0 = wi * S, c0 = wj * S;
            float s = 0.f, q = 0.f;
            for (int e = lane; e < K * K; e += 64) {
                int r = e / K, cc = e - r * K;
                float v = plane[(r0 + r) * WW + c0 + cc];
                s += v; q += v * v;
            }
            #pragma unroll
            for (int off = 32; off > 0; off >>= 1) {
                s += __shfl_down(s, off);
                q += __shfl_down(q, off);
            }
            if (lane == 0) {
                float inv  = 1.f / (K * K);
                float mean = s * inv;
                float var  = fmaxf(q * inv - mean * mean, 0.f);
                am += mean;
                as += sqrtf(var + EPSF);
            }
        }
        redA[tid] = am; redB[tid] = as;
        __syncthreads();
        for (int s = 128; s > 0; s >>= 1) {
            if (tid < s) { redA[tid] += redA[tid + s]; redB[tid] += redB[tid + s]; }
            __syncthreads();
        }
        if (tid == 0) {
            float inv = 1.f / NW;
            pooled[(1 * N + n) * 512 + c]        = redA[0] * inv;
            pooled[(1 * N + n) * 512 + 256 + c]  = redB[0] * inv;
        }
        __syncthreads();
    }

    // =============== K = 65, stride 32, out 2x2 (per-wave windows) ===============
    {
        const int K = 65, S = 32, OUTD = 2, NW = OUTD * OUTD;
        const int wave = tid >> 6, lane = tid & 63;
        float am = 0.f, as = 0.f;
        if (wave < NW) {
            int wi = wave / OUTD, wj = wave - wi * OUTD;
            int r0 = wi * S, c0 = wj * S;
            float s = 0.f, q = 0.f;
            for (int e = lane; e < K * K; e += 64) {
                int r = e / K, cc = e - r * K;
                float v = plane[(r0 + r) * WW + c0 + cc];
                s += v; q += v * v;
            }
            #pragma unroll
            for (int off = 32; off > 0; off >>= 1) {
                s += __shfl_down(s, off);
                q += __shfl_down(q, off);
            }
            if (lane == 0) {
                float inv  = 1.f / (K * K);
                float mean = s * inv;
                float var  = fmaxf(q * inv - mean * mean, 0.f);
                am = mean;
                as = sqrtf(var + EPSF);
            }
        }
        redA[tid] = am; redB[tid] = as;
        __syncthreads();
        for (int s = 128; s > 0; s >>= 1) {
            if (tid < s) { redA[tid] += redA[tid + s]; redB[tid] += redB[tid + s]; }
            __syncthreads();
        }
        if (tid == 0) {
            float inv = 1.f / NW;
            pooled[(2 * N + n) * 512 + c]        = redA[0] * inv;
            pooled[(2 * N + n) * 512 + 256 + c]  = redB[0] * inv;
        }
    }
}

__device__ __forceinline__ float leaky(float v) { return v > 0.f ? v : SLOPE * v; }

// One block per (k, n). 256 threads, 16 lanes per output dot-product.
__global__ __launch_bounds__(256) void mlp_kernel(const float* __restrict__ pooled,
                                                  const float* __restrict__ W1, const float* __restrict__ b1,
                                                  const float* __restrict__ W2, const float* __restrict__ b2,
                                                  const float* __restrict__ W3, const float* __restrict__ b3,
                                                  const float* __restrict__ W4, const float* __restrict__ b4,
                                                  const int* __restrict__ label,
                                                  float* __restrict__ losses,
                                                  int N) {
    __shared__ float x[512];
    __shared__ float h1[256];
    __shared__ float h2[256];
    __shared__ float h3[128];

    const int bk = blockIdx.x;
    const int k  = bk / N;
    const int n  = bk - k * N;
    const int tid = threadIdx.x;
    const int g = tid >> 4;        // 16 groups of 16 lanes
    const int l = tid & 15;

    for (int i = tid; i < 512; i += 256) x[i] = pooled[(k * N + n) * 512 + i];
    __syncthreads();

    // layer 1: 512 -> 256
    #pragma unroll
    for (int rep = 0; rep < 16; ++rep) {
        int o = g + 16 * rep;
        const float* w = &W1[((size_t)k * 256 + o) * 512];
        float s = 0.f;
        for (int j = l; j < 512; j += 16) s += w[j] * x[j];
        #pragma unroll
        for (int off = 8; off > 0; off >>= 1) s += __shfl_down(s, off, 16);
        if (l == 0) h1[o] = leaky(s + b1[k * 256 + o]);
    }
    __syncthreads();

    // layer 2: 256 -> 256
    #pragma unroll
    for (int rep = 0; rep < 16; ++rep) {
        int o = g + 16 * rep;
        const float* w = &W2[((size_t)k * 256 + o) * 256];
        float s = 0.f;
        for (int j = l; j < 256; j += 16) s += w[j] * h1[j];
        #pragma unroll
        for (int off = 8; off > 0; off >>= 1) s += __shfl_down(s, off, 16);
        if (l == 0) h2[o] = leaky(s + b2[k * 256 + o]);
    }
    __syncthreads();

    // layer 3: 256 -> 128
    #pragma unroll
    for (int rep = 0; rep < 8; ++rep) {
        int o = g + 16 * rep;
        const float* w = &W3[((size_t)k * 128 + o) * 256];
        float s = 0.f;
        for (int j = l; j < 256; j += 16) s += w[j] * h2[j];
        #pragma unroll
        for (int off = 8; off > 0; off >>= 1) s += __shfl_down(s, off, 16);
        if (l == 0) h3[o] = leaky(s + b3[k * 128 + o]);
    }
    __syncthreads();

    // layer 4: 128 -> 1 (products to LDS, serial sum by thread 0 for determinism)
    if (tid < 128) h1[tid] = W4[(size_t)k * 128 + tid] * h3[tid];
    __syncthreads();
    if (tid == 0) {
        float s = 0.f;
        for (int j = 0; j < 128; ++j) s += h1[j];
        float logit = s + b4[k];
        float y = (float)(*label);
        float sp = fmaxf(logit, 0.f) + log1pf(expf(-fabsf(logit)));
        losses[k * N + n] = sp - logit * y;
    }
}

__global__ void finalize_kernel(const float* __restrict__ losses, float* __restrict__ out, int N) {
    if (threadIdx.x == 0 && blockIdx.x == 0) {
        float tot = 0.f;
        for (int k = 0; k < 3; ++k) {
            float s = 0.f;
            for (int nn = 0; nn < N; ++nn) s += losses[k * N + nn];
            tot += s / (float)N;
        }
        out[0] = tot;
    }
}

extern "C" void kernel_launch(void* const* d_in, const int* in_sizes, int n_in,
                              void* d_out, int out_size, void* d_ws, size_t ws_size,
                              hipStream_t stream) {
    const float* feat = (const float*)d_in[0];
    const float* W1   = (const float*)d_in[1];
    const float* b1   = (const float*)d_in[2];
    const float* W2   = (const float*)d_in[3];
    const float* b2   = (const float*)d_in[4];
    const float* W3   = (const float*)d_in[5];
    const float* b3   = (const float*)d_in[6];
    const float* W4   = (const float*)d_in[7];
    const float* b4   = (const float*)d_in[8];
    const int* label  = (const int*)d_in[9];

    const int N = in_sizes[0] / (CCH * HH * WW);   // = 2

    float* pooled = (float*)d_ws;                  // [3][N][512]
    float* losses = pooled + (size_t)3 * N * 512;  // [3][N]

    stats_kernel<<<N * CCH, 256, 0, stream>>>(feat, pooled, N);
    mlp_kernel<<<3 * N, 256, 0, stream>>>(pooled, W1, b1, W2, b2, W3, b3, W4, b4,
                                          label, losses, N);
    finalize_kernel<<<1, 1, 0, stream>>>(losses, (float*)d_out, N);
}

// Round 2
// 58.063 us; speedup vs baseline: 3.8858x; 3.8858x over previous
//
#include <hip/hip_runtime.h>
#include <hip/hip_bf16.h>
#include <math.h>

#define CCH   256      // IN_CHANNELS
#define HH    128
#define WW    128
#define EPSF  1e-12f
#define SLOPE 0.2f

// pooled layout: [3][N][512]  (c -> mean part, 256+c -> std part)

__global__ __launch_bounds__(256) void stats_kernel(const float* __restrict__ feat,
                                                    float* __restrict__ pooled,
                                                    int N) {
    __shared__ float plane[HH * WW];          // 64 KB
    __shared__ float redA[256];
    __shared__ float redB[256];

    const int p   = blockIdx.x;               // n*C + c
    const int n   = p >> 8;                   // /256
    const int c   = p & 255;
    const int tid = threadIdx.x;

    // ---- stage plane into LDS (coalesced float4) ----
    const float4* src4 = reinterpret_cast<const float4*>(feat + (size_t)p * (HH * WW));
    float4* pl4 = reinterpret_cast<float4*>(plane);
    #pragma unroll
    for (int i = 0; i < (HH * WW / 4) / 256; ++i)
        pl4[tid + i * 256] = src4[tid + i * 256];
    __syncthreads();

    // =============== K = 3, stride 1, out 126x126 (per-thread windows) ===============
    {
        const int OUT = 126;
        float am = 0.f, as = 0.f;
        for (int idx = tid; idx < OUT * OUT; idx += 256) {
            int i = idx / OUT, j = idx - i * OUT;
            float s = 0.f, q = 0.f;
            #pragma unroll
            for (int di = 0; di < 3; ++di) {
                const float* row = &plane[(i + di) * WW + j];
                #pragma unroll
                for (int dj = 0; dj < 3; ++dj) { float v = row[dj]; s += v; q += v * v; }
            }
            float mean = s * (1.f / 9.f);
            float var  = fmaxf(q * (1.f / 9.f) - mean * mean, 0.f);
            am += mean;
            as += sqrtf(var + EPSF);
        }
        redA[tid] = am; redB[tid] = as;
        __syncthreads();
        for (int s = 128; s > 0; s >>= 1) {
            if (tid < s) { redA[tid] += redA[tid + s]; redB[tid] += redB[tid + s]; }
            __syncthreads();
        }
        if (tid == 0) {
            float inv = 1.f / (OUT * OUT);
            pooled[(0 * N + n) * 512 + c]        = redA[0] * inv;
            pooled[(0 * N + n) * 512 + 256 + c]  = redB[0] * inv;
        }
        __syncthreads();
    }

    // =============== K = 34, stride 16, out 6x6 (per-wave windows) ===============
    {
        const int K = 34, S = 16, OUTD = 6, NW = OUTD * OUTD;
        const int wave = tid >> 6, lane = tid & 63;
        float am = 0.f, as = 0.f;
        for (int w = wave; w < NW; w += 4) {
            int wi = w / OUTD, wj = w - wi * OUTD;
            int r0 = wi * S, c0 = wj * S;
            float s = 0.f, q = 0.f;
            for (int e = lane; e < K * K; e += 64) {
                int r = e / K, cc = e - r * K;
                float v = plane[(r0 + r) * WW + c0 + cc];
                s += v; q += v * v;
            }
            #pragma unroll
            for (int off = 32; off > 0; off >>= 1) {
                s += __shfl_down(s, off);
                q += __shfl_down(q, off);
            }
            if (lane == 0) {
                float inv  = 1.f / (K * K);
                float mean = s * inv;
                float var  = fmaxf(q * inv - mean * mean, 0.f);
                am += mean;
                as += sqrtf(var + EPSF);
            }
        }
        redA[tid] = am; redB[tid] = as;
        __syncthreads();
        for (int s = 128; s > 0; s >>= 1) {
            if (tid < s) { redA[tid] += redA[tid + s]; redB[tid] += redB[tid + s]; }
            __syncthreads();
        }
        if (tid == 0) {
            float inv = 1.f / NW;
            pooled[(1 * N + n) * 512 + c]        = redA[0] * inv;
            pooled[(1 * N + n) * 512 + 256 + c]  = redB[0] * inv;
        }
        __syncthreads();
    }

    // =============== K = 65, stride 32, out 2x2 (per-wave windows) ===============
    {
        const int K = 65, S = 32, OUTD = 2, NW = OUTD * OUTD;
        const int wave = tid >> 6, lane = tid & 63;
        float am = 0.f, as = 0.f;
        if (wave < NW) {
            int wi = wave / OUTD, wj = wave - wi * OUTD;
            int r0 = wi * S, c0 = wj * S;
            float s = 0.f, q = 0.f;
            for (int e = lane; e < K * K; e += 64) {
                int r = e / K, cc = e - r * K;
                float v = plane[(r0 + r) * WW + c0 + cc];
                s += v; q += v * v;
            }
            #pragma unroll
            for (int off = 32; off > 0; off >>= 1) {
                s += __shfl_down(s, off);
                q += __shfl_down(q, off);
            }
            if (lane == 0) {
                float inv  = 1.f / (K * K);
                float mean = s * inv;
                float var  = fmaxf(q * inv - mean * mean, 0.f);
                am = mean;
                as = sqrtf(var + EPSF);
            }
        }
        redA[tid] = am; redB[tid] = as;
        __syncthreads();
        for (int s = 128; s > 0; s >>= 1) {
            if (tid < s) { redA[tid] += redA[tid + s]; redB[tid] += redB[tid + s]; }
            __syncthreads();
        }
        if (tid == 0) {
            float inv = 1.f / NW;
            pooled[(2 * N + n) * 512 + c]        = redA[0] * inv;
            pooled[(2 * N + n) * 512 + 256 + c]  = redB[0] * inv;
        }
    }
}

__device__ __forceinline__ float leaky(float v) { return v > 0.f ? v : SLOPE * v; }

// One wave per output row (k, o); each wave computes the dot product for BOTH
// n samples from a single coalesced read of the weight row.
// xin: [3][N][DIN], xout: [3][N][DOUT], W: [3][DOUT][DIN], b: [3][DOUT]
__global__ __launch_bounds__(256) void layer_kernel(const float* __restrict__ W,
                                                    const float* __restrict__ b,
                                                    const float* __restrict__ xin,
                                                    float* __restrict__ xout,
                                                    int DIN, int DOUT, int N, int act) {
    const int wave = threadIdx.x >> 6, lane = threadIdx.x & 63;
    const int r = blockIdx.x * 4 + wave;           // row over 3*DOUT
    if (r >= 3 * DOUT) return;
    const int k = r / DOUT, o = r - k * DOUT;

    const float* w  = &W[((size_t)k * DOUT + o) * DIN];
    const float* x0 = &xin[(size_t)(k * N + 0) * DIN];
    const float* x1 = &xin[(size_t)(k * N + 1) * DIN];

    float s0 = 0.f, s1 = 0.f;
    for (int j = lane; j < DIN; j += 64) {
        float wv = w[j];
        s0 += wv * x0[j];
        s1 += wv * x1[j];
    }
    #pragma unroll
    for (int off = 32; off > 0; off >>= 1) {
        s0 += __shfl_down(s0, off);
        s1 += __shfl_down(s1, off);
    }
    if (lane == 0) {
        float bb = b[k * DOUT + o];
        float v0 = s0 + bb, v1 = s1 + bb;
        if (act) { v0 = leaky(v0); v1 = leaky(v1); }
        xout[(size_t)(k * N + 0) * DOUT + o] = v0;
        xout[(size_t)(k * N + 1) * DOUT + o] = v1;
    }
}

// Final layer 128->1 + softplus loss + deterministic sum. One block, 384 threads:
// one wave per (k, n).
__global__ __launch_bounds__(384) void final_kernel(const float* __restrict__ W4,
                                                    const float* __restrict__ b4,
                                                    const float* __restrict__ h3,
                                                    const int* __restrict__ label,
                                                    float* __restrict__ out, int N) {
    __shared__ float lossArr[8];
    const int wave = threadIdx.x >> 6, lane = threadIdx.x & 63;
    if (wave < 3 * N) {
        const int k = wave / N, n = wave - k * N;
        const float* w = &W4[(size_t)k * 128];
        const float* x = &h3[(size_t)(k * N + n) * 128];
        float s = w[lane] * x[lane] + w[lane + 64] * x[lane + 64];
        #pragma unroll
        for (int off = 32; off > 0; off >>= 1) s += __shfl_down(s, off);
        if (lane == 0) {
            float logit = s + b4[k];
            float y = (float)(*label);
            float sp = fmaxf(logit, 0.f) + log1pf(expf(-fabsf(logit)));
            lossArr[wave] = sp - logit * y;
        }
    }
    __syncthreads();
    if (threadIdx.x == 0) {
        float tot = 0.f;
        for (int k = 0; k < 3; ++k) {
            float s = 0.f;
            for (int nn = 0; nn < N; ++nn) s += lossArr[k * N + nn];
            tot += s / (float)N;
        }
        out[0] = tot;
    }
}

extern "C" void kernel_launch(void* const* d_in, const int* in_sizes, int n_in,
                              void* d_out, int out_size, void* d_ws, size_t ws_size,
                              hipStream_t stream) {
    const float* feat = (const float*)d_in[0];
    const float* W1   = (const float*)d_in[1];
    const float* b1   = (const float*)d_in[2];
    const float* W2   = (const float*)d_in[3];
    const float* b2   = (const float*)d_in[4];
    const float* W3   = (const float*)d_in[5];
    const float* b3   = (const float*)d_in[6];
    const float* W4   = (const float*)d_in[7];
    const float* b4   = (const float*)d_in[8];
    const int* label  = (const int*)d_in[9];

    const int N = in_sizes[0] / (CCH * HH * WW);   // = 2

    float* pooled = (float*)d_ws;                   // [3][N][512]
    float* h1     = pooled + (size_t)3 * N * 512;   // [3][N][256]
    float* h2     = h1     + (size_t)3 * N * 256;   // [3][N][256]
    float* h3     = h2     + (size_t)3 * N * 256;   // [3][N][128]

    stats_kernel<<<N * CCH, 256, 0, stream>>>(feat, pooled, N);

    // layer 1: 512 -> 256 : 3*256 = 768 rows, 4 waves/block -> 192 blocks
    layer_kernel<<<192, 256, 0, stream>>>(W1, b1, pooled, h1, 512, 256, N, 1);
    // layer 2: 256 -> 256
    layer_kernel<<<192, 256, 0, stream>>>(W2, b2, h1, h2, 256, 256, N, 1);
    // layer 3: 256 -> 128 : 384 rows -> 96 blocks
    layer_kernel<<<96, 256, 0, stream>>>(W3, b3, h2, h3, 256, 128, N, 1);
    // layer 4 + loss + finalize
    final_kernel<<<1, 384, 0, stream>>>(W4, b4, h3, label, (float*)d_out, N);
}

// Round 3
// 45.196 us; speedup vs baseline: 4.9920x; 1.2847x over previous
//
#include <hip/hip_runtime.h>
#include <hip/hip_bf16.h>
#include <math.h>

#define CCH   256      // IN_CHANNELS
#define HH    128
#define WW    128
#define EPSF  1e-12f
#define SLOPE 0.2f

// pooled layout: [3][N][512]  (c -> mean part, 256+c -> std part)

__global__ __launch_bounds__(512, 4) void stats_kernel(const float* __restrict__ feat,
                                                       float* __restrict__ pooled,
                                                       int N) {
    __shared__ float plane[HH * WW];          // 64 KB
    __shared__ float wredA[8];
    __shared__ float wredB[8];

    const int p    = blockIdx.x;              // n*C + c
    const int n    = p >> 8;
    const int c    = p & 255;
    const int tid  = threadIdx.x;
    const int wave = tid >> 6, lane = tid & 63;

    // ---- stage plane into LDS (coalesced float4) ----
    const float4* src4 = reinterpret_cast<const float4*>(feat + (size_t)p * (HH * WW));
    float4* pl4 = reinterpret_cast<float4*>(plane);
    #pragma unroll
    for (int i = 0; i < (HH * WW / 4) / 512; ++i)
        pl4[tid + i * 512] = src4[tid + i * 512];
    __syncthreads();

    // =============== K = 3, stride 1, out 126x126 ===============
    // thread = (row-group g, column j); rolling FIFO of per-row 3-element sums.
    {
        const int OUT = 126;
        float am = 0.f, as = 0.f;
        const int j = tid & 127;
        const int g = tid >> 7;               // 0..3
        if (j < OUT) {
            const int i0 = g * 32;
            const int i1 = (i0 + 32 < OUT) ? (i0 + 32) : OUT;   // g=3 -> 30 rows
            float r0s, r0q, r1s, r1q;
            {
                const float* row = &plane[i0 * WW + j];
                float a = row[0], b = row[1], d = row[2];
                r0s = a + b + d; r0q = a * a + b * b + d * d;
                row += WW;
                a = row[0]; b = row[1]; d = row[2];
                r1s = a + b + d; r1q = a * a + b * b + d * d;
            }
            const float* row = &plane[(i0 + 2) * WW + j];
            for (int i = i0; i < i1; ++i, row += WW) {
                float a = row[0], b = row[1], d = row[2];
                float r2s = a + b + d, r2q = a * a + b * b + d * d;
                float s = r0s + r1s + r2s;
                float q = r0q + r1q + r2q;
                float mean = s * (1.f / 9.f);
                float var  = fmaxf(q * (1.f / 9.f) - mean * mean, 0.f);
                am += mean;
                as += sqrtf(var + EPSF);
                r0s = r1s; r0q = r1q; r1s = r2s; r1q = r2q;
            }
        }
        #pragma unroll
        for (int off = 32; off > 0; off >>= 1) {
            am += __shfl_down(am, off);
            as += __shfl_down(as, off);
        }
        if (lane == 0) { wredA[wave] = am; wredB[wave] = as; }
        __syncthreads();
        if (tid == 0) {
            float A = 0.f, B = 0.f;
            #pragma unroll
            for (int w = 0; w < 8; ++w) { A += wredA[w]; B += wredB[w]; }
            float inv = 1.f / (OUT * OUT);
            pooled[(0 * N + n) * 512 + c]       = A * inv;
            pooled[(0 * N + n) * 512 + 256 + c] = B * inv;
        }
        __syncthreads();
    }

    // =============== K = 34, stride 16, out 6x6 (per-wave windows) ===============
    {
        const int K = 34, S = 16, OUTD = 6, NW = OUTD * OUTD;
        float am = 0.f, as = 0.f;
        for (int w = wave; w < NW; w += 8) {
            int wi = w / OUTD, wj = w - wi * OUTD;
            int r0 = wi * S, c0 = wj * S;
            float s = 0.f, q = 0.f;
            for (int e = lane; e < K * K; e += 64) {
                int r = e / K, cc = e - r * K;
                float v = plane[(r0 + r) * WW + c0 + cc];
                s += v; q += v * v;
            }
            #pragma unroll
            for (int off = 32; off > 0; off >>= 1) {
                s += __shfl_down(s, off);
                q += __shfl_down(q, off);
            }
            if (lane == 0) {
                float inv  = 1.f / (K * K);
                float mean = s * inv;
                float var  = fmaxf(q * inv - mean * mean, 0.f);
                am += mean;
                as += sqrtf(var + EPSF);
            }
        }
        if (lane == 0) { wredA[wave] = am; wredB[wave] = as; }
        __syncthreads();
        if (tid == 0) {
            float A = 0.f, B = 0.f;
            #pragma unroll
            for (int w = 0; w < 8; ++w) { A += wredA[w]; B += wredB[w]; }
            float inv = 1.f / NW;
            pooled[(1 * N + n) * 512 + c]       = A * inv;
            pooled[(1 * N + n) * 512 + 256 + c] = B * inv;
        }
        __syncthreads();
    }

    // =============== K = 65, stride 32, out 2x2 (per-wave windows) ===============
    {
        const int K = 65, S = 32, OUTD = 2, NW = OUTD * OUTD;
        float am = 0.f, as = 0.f;
        if (wave < NW) {
            int wi = wave / OUTD, wj = wave - wi * OUTD;
            int r0 = wi * S, c0 = wj * S;
            float s = 0.f, q = 0.f;
            for (int e = lane; e < K * K; e += 64) {
                int r = e / K, cc = e - r * K;
                float v = plane[(r0 + r) * WW + c0 + cc];
                s += v; q += v * v;
            }
            #pragma unroll
            for (int off = 32; off > 0; off >>= 1) {
                s += __shfl_down(s, off);
                q += __shfl_down(q, off);
            }
            if (lane == 0) {
                float inv  = 1.f / (K * K);
                float mean = s * inv;
                float var  = fmaxf(q * inv - mean * mean, 0.f);
                am = mean;
                as = sqrtf(var + EPSF);
            }
        }
        if (lane == 0) { wredA[wave] = am; wredB[wave] = as; }
        __syncthreads();
        if (tid == 0) {
            float A = 0.f, B = 0.f;
            #pragma unroll
            for (int w = 0; w < 4; ++w) { A += wredA[w]; B += wredB[w]; }
            float inv = 1.f / NW;
            pooled[(2 * N + n) * 512 + c]       = A * inv;
            pooled[(2 * N + n) * 512 + 256 + c] = B * inv;
        }
    }
}

__device__ __forceinline__ float leaky(float v) { return v > 0.f ? v : SLOPE * v; }

// One wave per output row (k, o); each wave computes the dot product for BOTH
// n samples from a single coalesced read of the weight row.
__global__ __launch_bounds__(256) void layer_kernel(const float* __restrict__ W,
                                                    const float* __restrict__ b,
                                                    const float* __restrict__ xin,
                                                    float* __restrict__ xout,
                                                    int DIN, int DOUT, int N, int act) {
    const int wave = threadIdx.x >> 6, lane = threadIdx.x & 63;
    const int r = blockIdx.x * 4 + wave;           // row over 3*DOUT
    if (r >= 3 * DOUT) return;
    const int k = r / DOUT, o = r - k * DOUT;

    const float* w  = &W[((size_t)k * DOUT + o) * DIN];
    const float* x0 = &xin[(size_t)(k * N + 0) * DIN];
    const float* x1 = &xin[(size_t)(k * N + 1) * DIN];

    float s0 = 0.f, s1 = 0.f;
    for (int j = lane; j < DIN; j += 64) {
        float wv = w[j];
        s0 += wv * x0[j];
        s1 += wv * x1[j];
    }
    #pragma unroll
    for (int off = 32; off > 0; off >>= 1) {
        s0 += __shfl_down(s0, off);
        s1 += __shfl_down(s1, off);
    }
    if (lane == 0) {
        float bb = b[k * DOUT + o];
        float v0 = s0 + bb, v1 = s1 + bb;
        if (act) { v0 = leaky(v0); v1 = leaky(v1); }
        xout[(size_t)(k * N + 0) * DOUT + o] = v0;
        xout[(size_t)(k * N + 1) * DOUT + o] = v1;
    }
}

// Final layer 128->1 + softplus loss + deterministic sum. One block, 384 threads.
__global__ __launch_bounds__(384) void final_kernel(const float* __restrict__ W4,
                                                    const float* __restrict__ b4,
                                                    const float* __restrict__ h3,
                                                    const int* __restrict__ label,
                                                    float* __restrict__ out, int N) {
    __shared__ float lossArr[8];
    const int wave = threadIdx.x >> 6, lane = threadIdx.x & 63;
    if (wave < 3 * N) {
        const int k = wave / N, n = wave - k * N;
        const float* w = &W4[(size_t)k * 128];
        const float* x = &h3[(size_t)(k * N + n) * 128];
        float s = w[lane] * x[lane] + w[lane + 64] * x[lane + 64];
        #pragma unroll
        for (int off = 32; off > 0; off >>= 1) s += __shfl_down(s, off);
        if (lane == 0) {
            float logit = s + b4[k];
            float y = (float)(*label);
            float sp = fmaxf(logit, 0.f) + log1pf(expf(-fabsf(logit)));
            lossArr[wave] = sp - logit * y;
        }
    }
    __syncthreads();
    if (threadIdx.x == 0) {
        float tot = 0.f;
        for (int k = 0; k < 3; ++k) {
            float s = 0.f;
            for (int nn = 0; nn < N; ++nn) s += lossArr[k * N + nn];
            tot += s / (float)N;
        }
        out[0] = tot;
    }
}

extern "C" void kernel_launch(void* const* d_in, const int* in_sizes, int n_in,
                              void* d_out, int out_size, void* d_ws, size_t ws_size,
                              hipStream_t stream) {
    const float* feat = (const float*)d_in[0];
    const float* W1   = (const float*)d_in[1];
    const float* b1   = (const float*)d_in[2];
    const float* W2   = (const float*)d_in[3];
    const float* b2   = (const float*)d_in[4];
    const float* W3   = (const float*)d_in[5];
    const float* b3   = (const float*)d_in[6];
    const float* W4   = (const float*)d_in[7];
    const float* b4   = (const float*)d_in[8];
    const int* label  = (const int*)d_in[9];

    const int N = in_sizes[0] / (CCH * HH * WW);   // = 2

    float* pooled = (float*)d_ws;                   // [3][N][512]
    float* h1     = pooled + (size_t)3 * N * 512;   // [3][N][256]
    float* h2     = h1     + (size_t)3 * N * 256;   // [3][N][256]
    float* h3     = h2     + (size_t)3 * N * 256;   // [3][N][128]

    stats_kernel<<<N * CCH, 512, 0, stream>>>(feat, pooled, N);

    layer_kernel<<<192, 256, 0, stream>>>(W1, b1, pooled, h1, 512, 256, N, 1);
    layer_kernel<<<192, 256, 0, stream>>>(W2, b2, h1, h2, 256, 256, N, 1);
    layer_kernel<<<96, 256, 0, stream>>>(W3, b3, h2, h3, 256, 128, N, 1);
    final_kernel<<<1, 384, 0, stream>>>(W4, b4, h3, label, (float*)d_out, N);
}

// Round 4
// 32.621 us; speedup vs baseline: 6.9163x; 1.3855x over previous
//
#include <hip/hip_runtime.h>
#include <hip/hip_bf16.h>
#include <math.h>

#define CCH   256      // IN_CHANNELS
#define HH    128
#define WW    128
#define EPSF  1e-12f
#define EPS81 8.1e-11f // 81 * 1e-12
#define SLOPE 0.2f

// pooled layout: [3][N][512]  (c -> mean part, 256+c -> std part)

__device__ __forceinline__ void k3_loadrow(const float* __restrict__ plane, int r, int jb,
                                           float4& rs, float4& rq) {
    const float* rp = &plane[r * WW + jb];
    float4 v = *reinterpret_cast<const float4*>(rp);       // cols jb..jb+3 (16B aligned)
    float2 w = *reinterpret_cast<const float2*>(rp + 4);   // cols jb+4, jb+5 (8B aligned)
    float t12 = v.y + v.z, t34 = v.w + w.x;
    rs.x = v.x + t12; rs.y = t12 + v.w; rs.z = v.z + t34; rs.w = t34 + w.y;
    float y0 = v.x * v.x, y1 = v.y * v.y, y2 = v.z * v.z;
    float y3 = v.w * v.w, y4 = w.x * w.x, y5 = w.y * w.y;
    float u12 = y1 + y2, u34 = y3 + y4;
    rq.x = y0 + u12; rq.y = u12 + y3; rq.z = y2 + u34; rq.w = u34 + y5;
}

__device__ __forceinline__ void win_acc(float S, float Q, float wm, float& aS, float& aD) {
    // std*9 = sqrt(max(9Q - S^2, 0) + 81*eps); accumulate masked
    float d = fmaxf(fmaf(S, -S, 9.f * Q), 0.f);
    aS = fmaf(wm, S, aS);
    aD = fmaf(wm, sqrtf(d + EPS81), aD);
}

__global__ __launch_bounds__(512, 4) void stats_kernel(const float* __restrict__ feat,
                                                       float* __restrict__ pooled,
                                                       int N) {
    __shared__ float plane[HH * WW + 8];      // 64 KB + pad
    __shared__ float wp[8][6];

    const int p    = blockIdx.x;              // n*C + c
    const int n    = p >> 8;
    const int c    = p & 255;
    const int tid  = threadIdx.x;
    const int wave = tid >> 6, lane = tid & 63;

    // ---- stage plane into LDS (coalesced float4) ----
    {
        const float4* src4 = reinterpret_cast<const float4*>(feat + (size_t)p * (HH * WW));
        float4* pl4 = reinterpret_cast<float4*>(plane);
        #pragma unroll
        for (int i = 0; i < 8; ++i)
            pl4[tid + i * 512] = src4[tid + i * 512];
        if (tid < 8) plane[HH * WW + tid] = 0.f;
    }
    __syncthreads();

    // =============== K = 3, stride 1, out 126x126 ===============
    // thread = (strip s: window cols 4s..4s+3, rowgroup g: window rows 8g..8g+7)
    float a3S = 0.f, a3D = 0.f;
    {
        const int s  = tid & 31;
        const int g  = tid >> 5;              // 0..15
        const int jb = s << 2;
        const float wm2 = (s < 31) ? 1.f : 0.f;  // window cols 4s+2, 4s+3 invalid only for s=31
        const int i0 = g << 3;
        float4 r0s, r0q, r1s, r1q;
        k3_loadrow(plane, i0,     jb, r0s, r0q);
        k3_loadrow(plane, i0 + 1, jb, r1s, r1q);
        #pragma unroll 2
        for (int t = 0; t < 8; ++t) {
            int i = i0 + t;
            if (i < 126) {
                float4 r2s, r2q;
                k3_loadrow(plane, i + 2, jb, r2s, r2q);
                float Sx = r0s.x + r1s.x + r2s.x, Qx = r0q.x + r1q.x + r2q.x;
                float Sy = r0s.y + r1s.y + r2s.y, Qy = r0q.y + r1q.y + r2q.y;
                float Sz = r0s.z + r1s.z + r2s.z, Qz = r0q.z + r1q.z + r2q.z;
                float Sw = r0s.w + r1s.w + r2s.w, Qw = r0q.w + r1q.w + r2q.w;
                win_acc(Sx, Qx, 1.f, a3S, a3D);
                win_acc(Sy, Qy, 1.f, a3S, a3D);
                win_acc(Sz, Qz, wm2, a3S, a3D);
                win_acc(Sw, Qw, wm2, a3S, a3D);
                r0s = r1s; r0q = r1q; r1s = r2s; r1q = r2q;
            }
        }
    }

    // =============== K = 34, stride 16, out 6x6 (windows round-robin over 8 waves) ===============
    float am34 = 0.f, as34 = 0.f;
    for (int w = wave; w < 36; w += 8) {
        int wi = w / 6, wj = w - 6 * wi;
        int r0 = wi << 4, c0 = wj << 4;
        float S = 0.f, Q = 0.f;
        #pragma unroll
        for (int it = 0; it < 5; ++it) {
            int t = lane + (it << 6);
            if (t < 306) {                     // 34 rows x 9 float4-slots
                int r = t / 9, c4 = t - 9 * r;
                const float* rp = &plane[(r0 + r) * WW + c0 + (c4 << 2)];
                float4 v = *reinterpret_cast<const float4*>(rp);
                if (c4 == 8) { v.z = 0.f; v.w = 0.f; }   // cols 34,35 of window masked
                S += (v.x + v.y) + (v.z + v.w);
                Q = fmaf(v.x, v.x, Q); Q = fmaf(v.y, v.y, Q);
                Q = fmaf(v.z, v.z, Q); Q = fmaf(v.w, v.w, Q);
            }
        }
        #pragma unroll
        for (int off = 32; off > 0; off >>= 1) {
            S += __shfl_down(S, off);
            Q += __shfl_down(Q, off);
        }
        if (lane == 0) {
            const float inv = 1.f / 1156.f;
            float mean = S * inv;
            float var  = fmaxf(fmaf(-mean, mean, Q * inv), 0.f);
            am34 += mean;
            as34 += sqrtf(var + EPSF);
        }
    }

    // =============== K = 65, stride 32, out 2x2 (one window per wave, waves 4..7) ===============
    float m65 = 0.f, s65 = 0.f;
    if (wave >= 4) {
        int w  = wave - 4;
        int wi = w >> 1, wj = w & 1;
        int r0 = wi << 5, c0 = wj << 5;
        float S = 0.f, Q = 0.f;
        #pragma unroll
        for (int it = 0; it < 18; ++it) {
            int t = lane + (it << 6);
            if (t < 1105) {                    // 65 rows x 17 float4-slots
                int r = t / 17, c4 = t - 17 * r;
                const float* rp = &plane[(r0 + r) * WW + c0 + (c4 << 2)];
                float4 v = *reinterpret_cast<const float4*>(rp);
                if (c4 == 16) { v.y = 0.f; v.z = 0.f; v.w = 0.f; } // cols 65..67 masked
                S += (v.x + v.y) + (v.z + v.w);
                Q = fmaf(v.x, v.x, Q); Q = fmaf(v.y, v.y, Q);
                Q = fmaf(v.z, v.z, Q); Q = fmaf(v.w, v.w, Q);
            }
        }
        #pragma unroll
        for (int off = 32; off > 0; off >>= 1) {
            S += __shfl_down(S, off);
            Q += __shfl_down(Q, off);
        }
        if (lane == 0) {
            const float inv = 1.f / 4225.f;
            float mean = S * inv;
            float var  = fmaxf(fmaf(-mean, mean, Q * inv), 0.f);
            m65 = mean;
            s65 = sqrtf(var + EPSF);
        }
    }

    // ---- reduce K3 partials across the wave, then one barrier + final reduce ----
    #pragma unroll
    for (int off = 32; off > 0; off >>= 1) {
        a3S += __shfl_down(a3S, off);
        a3D += __shfl_down(a3D, off);
    }
    if (lane == 0) {
        wp[wave][0] = a3S; wp[wave][1] = a3D;
        wp[wave][2] = am34; wp[wave][3] = as34;
        wp[wave][4] = m65;  wp[wave][5] = s65;
    }
    __syncthreads();
    if (tid == 0) {
        float A3 = 0.f, D3 = 0.f, M34 = 0.f, S34 = 0.f, M65 = 0.f, S65 = 0.f;
        #pragma unroll
        for (int w = 0; w < 8; ++w) {
            A3 += wp[w][0]; D3 += wp[w][1];
            M34 += wp[w][2]; S34 += wp[w][3];
            M65 += wp[w][4]; S65 += wp[w][5];
        }
        const float inv3 = 1.f / (9.f * 126.f * 126.f);
        pooled[(0 * N + n) * 512 + c]       = A3 * inv3;
        pooled[(0 * N + n) * 512 + 256 + c] = D3 * inv3;
        pooled[(1 * N + n) * 512 + c]       = M34 * (1.f / 36.f);
        pooled[(1 * N + n) * 512 + 256 + c] = S34 * (1.f / 36.f);
        pooled[(2 * N + n) * 512 + c]       = M65 * 0.25f;
        pooled[(2 * N + n) * 512 + 256 + c] = S65 * 0.25f;
    }
}

__device__ __forceinline__ float leaky(float v) { return v > 0.f ? v : SLOPE * v; }

// One wave per output row (k, o); float4 loads; both n samples per weight read.
__global__ __launch_bounds__(256) void layer_kernel(const float* __restrict__ W,
                                                    const float* __restrict__ b,
                                                    const float* __restrict__ xin,
                                                    float* __restrict__ xout,
                                                    int DIN, int DOUT, int act) {
    const int wave = threadIdx.x >> 6, lane = threadIdx.x & 63;
    const int r = blockIdx.x * 4 + wave;           // row over 3*DOUT
    if (r >= 3 * DOUT) return;
    const int k = r / DOUT, o = r - k * DOUT;
    const int DIN4 = DIN >> 2;

    const float4* w4  = reinterpret_cast<const float4*>(W + ((size_t)k * DOUT + o) * DIN);
    const float4* x04 = reinterpret_cast<const float4*>(xin + (size_t)(k * 2 + 0) * DIN);
    const float4* x14 = reinterpret_cast<const float4*>(xin + (size_t)(k * 2 + 1) * DIN);

    float s0 = 0.f, s1 = 0.f;
    for (int j = lane; j < DIN4; j += 64) {
        float4 wv = w4[j], a = x04[j], d = x14[j];
        s0 = fmaf(wv.x, a.x, s0); s0 = fmaf(wv.y, a.y, s0);
        s0 = fmaf(wv.z, a.z, s0); s0 = fmaf(wv.w, a.w, s0);
        s1 = fmaf(wv.x, d.x, s1); s1 = fmaf(wv.y, d.y, s1);
        s1 = fmaf(wv.z, d.z, s1); s1 = fmaf(wv.w, d.w, s1);
    }
    #pragma unroll
    for (int off = 32; off > 0; off >>= 1) {
        s0 += __shfl_down(s0, off);
        s1 += __shfl_down(s1, off);
    }
    if (lane == 0) {
        float bb = b[k * DOUT + o];
        float v0 = s0 + bb, v1 = s1 + bb;
        if (act) { v0 = leaky(v0); v1 = leaky(v1); }
        xout[(size_t)(k * 2 + 0) * DOUT + o] = v0;
        xout[(size_t)(k * 2 + 1) * DOUT + o] = v1;
    }
}

// Final layer 128->1 + softplus loss + deterministic sum. One block, 384 threads.
__global__ __launch_bounds__(384) void final_kernel(const float* __restrict__ W4,
                                                    const float* __restrict__ b4,
                                                    const float* __restrict__ h3,
                                                    const int* __restrict__ label,
                                                    float* __restrict__ out, int N) {
    __shared__ float lossArr[8];
    const int wave = threadIdx.x >> 6, lane = threadIdx.x & 63;
    if (wave < 3 * N) {
        const int k = wave / N, n = wave - k * N;
        const float* w = &W4[(size_t)k * 128];
        const float* x = &h3[(size_t)(k * N + n) * 128];
        float s = w[lane] * x[lane] + w[lane + 64] * x[lane + 64];
        #pragma unroll
        for (int off = 32; off > 0; off >>= 1) s += __shfl_down(s, off);
        if (lane == 0) {
            float logit = s + b4[k];
            float y = (float)(*label);
            float sp = fmaxf(logit, 0.f) + log1pf(expf(-fabsf(logit)));
            lossArr[wave] = sp - logit * y;
        }
    }
    __syncthreads();
    if (threadIdx.x == 0) {
        float tot = 0.f;
        for (int k = 0; k < 3; ++k) {
            float s = 0.f;
            for (int nn = 0; nn < N; ++nn) s += lossArr[k * N + nn];
            tot += s / (float)N;
        }
        out[0] = tot;
    }
}

extern "C" void kernel_launch(void* const* d_in, const int* in_sizes, int n_in,
                              void* d_out, int out_size, void* d_ws, size_t ws_size,
                              hipStream_t stream) {
    const float* feat = (const float*)d_in[0];
    const float* W1   = (const float*)d_in[1];
    const float* b1   = (const float*)d_in[2];
    const float* W2   = (const float*)d_in[3];
    const float* b2   = (const float*)d_in[4];
    const float* W3   = (const float*)d_in[5];
    const float* b3   = (const float*)d_in[6];
    const float* W4   = (const float*)d_in[7];
    const float* b4   = (const float*)d_in[8];
    const int* label  = (const int*)d_in[9];

    const int N = in_sizes[0] / (CCH * HH * WW);   // = 2

    float* pooled = (float*)d_ws;                   // [3][N][512]
    float* h1     = pooled + (size_t)3 * N * 512;   // [3][N][256]
    float* h2     = h1     + (size_t)3 * N * 256;   // [3][N][256]
    float* h3     = h2     + (size_t)3 * N * 256;   // [3][N][128]

    stats_kernel<<<N * CCH, 512, 0, stream>>>(feat, pooled, N);

    layer_kernel<<<192, 256, 0, stream>>>(W1, b1, pooled, h1, 512, 256, 1);
    layer_kernel<<<192, 256, 0, stream>>>(W2, b2, h1, h2, 256, 256, 1);
    layer_kernel<<<96, 256, 0, stream>>>(W3, b3, h2, h3, 256, 128, 1);
    final_kernel<<<1, 384, 0, stream>>>(W4, b4, h3, label, (float*)d_out, N);
}